// Round 1
// baseline (679.855 us; speedup 1.0000x reference)
//
#include <hip/hip_runtime.h>
#include <stdint.h>

// Magnitude pruning: mag = (t*magnitude + |x|)/(t+1); threshold = k-th smallest
// mag (k from sparsity); out = x * (mag >= threshold).
// Exact selection via 2-level radix histogram (15 high bits, 17 low bits) on the
// monotonic unsigned key of mag. All control flow stays on-device (graph-safe).

#define LO_BITS 17
#define NB_HI   (1 << (32 - LO_BITS))   // 32768 bins, top 15 bits
#define NB_LO   (1 << LO_BITS)          // 131072 bins, low 17 bits

__device__ __forceinline__ uint32_t fkey(float f) {
    uint32_t u = __float_as_uint(f);
    return (u & 0x80000000u) ? ~u : (u | 0x80000000u);
}

__device__ __forceinline__ float magf(float x, float g, float tf, float den) {
    return (tf * g + fabsf(x)) / den;
}

// Pass 1: histogram of top 15 key bits. Packed u16-pair LDS histogram (64 KiB).
// Per-block element count < 65536 (grid=1024 blocks) so u16 halves can't overflow.
__global__ __launch_bounds__(1024) void hist_hi_kernel(
    const float* __restrict__ x, const float* __restrict__ g,
    const int* __restrict__ tptr, uint32_t* __restrict__ hist_hi, int n)
{
    __shared__ uint32_t lh[NB_HI / 2];
    for (int i = threadIdx.x; i < NB_HI / 2; i += blockDim.x) lh[i] = 0;
    __syncthreads();
    const float tf  = (float)tptr[0];
    const float den = tf + 1.0f;
    const int n4 = n >> 2;
    const float4* x4 = (const float4*)x;
    const float4* g4 = (const float4*)g;
    const int gid = blockIdx.x * blockDim.x + threadIdx.x;
    const int stride = gridDim.x * blockDim.x;
    for (int i = gid; i < n4; i += stride) {
        float4 xv = x4[i], gv = g4[i];
        uint32_t b0 = fkey(magf(xv.x, gv.x, tf, den)) >> LO_BITS;
        uint32_t b1 = fkey(magf(xv.y, gv.y, tf, den)) >> LO_BITS;
        uint32_t b2 = fkey(magf(xv.z, gv.z, tf, den)) >> LO_BITS;
        uint32_t b3 = fkey(magf(xv.w, gv.w, tf, den)) >> LO_BITS;
        atomicAdd(&lh[b0 >> 1], 1u << ((b0 & 1) * 16));
        atomicAdd(&lh[b1 >> 1], 1u << ((b1 & 1) * 16));
        atomicAdd(&lh[b2 >> 1], 1u << ((b2 & 1) * 16));
        atomicAdd(&lh[b3 >> 1], 1u << ((b3 & 1) * 16));
    }
    for (int i = (n4 << 2) + gid; i < n; i += stride) {   // tail (n%4, none here)
        uint32_t b = fkey(magf(x[i], g[i], tf, den)) >> LO_BITS;
        atomicAdd(&lh[b >> 1], 1u << ((b & 1) * 16));
    }
    __syncthreads();
    for (int i = threadIdx.x; i < NB_HI / 2; i += blockDim.x) {
        uint32_t v = lh[i];
        uint32_t lo = v & 0xffffu, hi = v >> 16;
        if (lo) atomicAdd(&hist_hi[2 * i],     lo);
        if (hi) atomicAdd(&hist_hi[2 * i + 1], hi);
    }
}

// Single-block scan: find bin where cumulative count crosses kk.
// phase 0: kk from sparsity (replicates floor(s*n-1) clip semantics);
//          writes ctl[0]=hi_bin, ctl[1]=remaining count.
// phase 1: kk = ctl[1]; writes ctl[2] = full 32-bit threshold key.
__global__ __launch_bounds__(1024) void scan_kernel(
    const uint32_t* __restrict__ hist, uint32_t* __restrict__ ctl,
    const float* __restrict__ sparsity, int nbins, int phase, int n)
{
    const int tid = threadIdx.x;
    const int bpt = nbins >> 10;          // bins per thread (32 or 128)
    uint32_t kk;
    if (phase == 0) {
        float s = sparsity[0];
        float v = floorf(s * (float)n - 1.0f);   // matches jnp: mul, sub, floor in f32
        long long idx = (long long)v;
        if (idx < 0) idx = 0;
        if (idx > (long long)(n - 1)) idx = n - 1;
        kk = (uint32_t)(idx + 1);                 // 1-based rank
    } else {
        kk = ctl[1];
    }
    const int base = tid * bpt;
    uint32_t s = 0;
    for (int j = 0; j < bpt; ++j) s += hist[base + j];
    __shared__ uint32_t tmp[1024];
    tmp[tid] = s;
    __syncthreads();
    for (int off = 1; off < 1024; off <<= 1) {    // Hillis-Steele inclusive scan
        uint32_t v = (tid >= off) ? tmp[tid - off] : 0u;
        __syncthreads();
        tmp[tid] += v;
        __syncthreads();
    }
    const uint32_t incl = tmp[tid];
    const uint32_t excl = incl - s;
    if (excl < kk && incl >= kk) {                // exactly one thread
        uint32_t running = excl;
        for (int j = 0; j < bpt; ++j) {
            uint32_t c = hist[base + j];
            if (running + c >= kk) {
                uint32_t bin = (uint32_t)(base + j);
                if (phase == 0) { ctl[0] = bin; ctl[1] = kk - running; }
                else            { ctl[2] = (ctl[0] << LO_BITS) | bin; }
                break;
            }
            running += c;
        }
    }
}

// Pass 2: histogram of low 17 bits for elements whose top bits match ctl[0].
__global__ __launch_bounds__(512) void hist_lo_kernel(
    const float* __restrict__ x, const float* __restrict__ g,
    const int* __restrict__ tptr, const uint32_t* __restrict__ ctl,
    uint32_t* __restrict__ hist_lo, int n)
{
    const uint32_t b   = ctl[0];
    const float tf  = (float)tptr[0];
    const float den = tf + 1.0f;
    const int n4 = n >> 2;
    const float4* x4 = (const float4*)x;
    const float4* g4 = (const float4*)g;
    const int gid = blockIdx.x * blockDim.x + threadIdx.x;
    const int stride = gridDim.x * blockDim.x;
    for (int i = gid; i < n4; i += stride) {
        float4 xv = x4[i], gv = g4[i];
        uint32_t k0 = fkey(magf(xv.x, gv.x, tf, den));
        uint32_t k1 = fkey(magf(xv.y, gv.y, tf, den));
        uint32_t k2 = fkey(magf(xv.z, gv.z, tf, den));
        uint32_t k3 = fkey(magf(xv.w, gv.w, tf, den));
        if ((k0 >> LO_BITS) == b) atomicAdd(&hist_lo[k0 & (NB_LO - 1)], 1u);
        if ((k1 >> LO_BITS) == b) atomicAdd(&hist_lo[k1 & (NB_LO - 1)], 1u);
        if ((k2 >> LO_BITS) == b) atomicAdd(&hist_lo[k2 & (NB_LO - 1)], 1u);
        if ((k3 >> LO_BITS) == b) atomicAdd(&hist_lo[k3 & (NB_LO - 1)], 1u);
    }
    for (int i = (n4 << 2) + gid; i < n; i += stride) {
        uint32_t k = fkey(magf(x[i], g[i], tf, den));
        if ((k >> LO_BITS) == b) atomicAdd(&hist_lo[k & (NB_LO - 1)], 1u);
    }
}

// Pass 3: out = x * (key >= K ? 1 : 0). Multiply keeps -0.0 semantics identical
// to the reference's x*mask.
__global__ __launch_bounds__(512) void apply_kernel(
    const float* __restrict__ x, const float* __restrict__ g,
    const int* __restrict__ tptr, const uint32_t* __restrict__ ctl,
    float* __restrict__ out, int n)
{
    const uint32_t K = ctl[2];
    const float tf  = (float)tptr[0];
    const float den = tf + 1.0f;
    const int n4 = n >> 2;
    const float4* x4 = (const float4*)x;
    const float4* g4 = (const float4*)g;
    float4* o4 = (float4*)out;
    const int gid = blockIdx.x * blockDim.x + threadIdx.x;
    const int stride = gridDim.x * blockDim.x;
    for (int i = gid; i < n4; i += stride) {
        float4 xv = x4[i], gv = g4[i];
        float4 o;
        o.x = xv.x * ((fkey(magf(xv.x, gv.x, tf, den)) >= K) ? 1.0f : 0.0f);
        o.y = xv.y * ((fkey(magf(xv.y, gv.y, tf, den)) >= K) ? 1.0f : 0.0f);
        o.z = xv.z * ((fkey(magf(xv.z, gv.z, tf, den)) >= K) ? 1.0f : 0.0f);
        o.w = xv.w * ((fkey(magf(xv.w, gv.w, tf, den)) >= K) ? 1.0f : 0.0f);
        o4[i] = o;
    }
    for (int i = (n4 << 2) + gid; i < n; i += stride) {
        out[i] = x[i] * ((fkey(magf(x[i], g[i], tf, den)) >= K) ? 1.0f : 0.0f);
    }
}

extern "C" void kernel_launch(void* const* d_in, const int* in_sizes, int n_in,
                              void* d_out, int out_size, void* d_ws, size_t ws_size,
                              hipStream_t stream)
{
    const float* x  = (const float*)d_in[0];
    const float* g  = (const float*)d_in[1];
    const float* sp = (const float*)d_in[2];
    // d_in[3] = mask input: unused by the reference computation.
    const int*   t  = (const int*)d_in[4];
    float* out = (float*)d_out;
    const int n = in_sizes[0];

    uint32_t* hist_hi = (uint32_t*)d_ws;
    uint32_t* hist_lo = hist_hi + NB_HI;
    uint32_t* ctl     = hist_lo + NB_LO;    // ctl[0]=hi bin, ctl[1]=rem k, ctl[2]=key

    hipMemsetAsync(d_ws, 0, (size_t)(NB_HI + NB_LO + 3) * sizeof(uint32_t), stream);
    hist_hi_kernel<<<1024, 1024, 0, stream>>>(x, g, t, hist_hi, n);
    scan_kernel<<<1, 1024, 0, stream>>>(hist_hi, ctl, sp, NB_HI, 0, n);
    hist_lo_kernel<<<2048, 512, 0, stream>>>(x, g, t, ctl, hist_lo, n);
    scan_kernel<<<1, 1024, 0, stream>>>(hist_lo, ctl, sp, NB_LO, 1, n);
    apply_kernel<<<2048, 512, 0, stream>>>(x, g, t, ctl, out, n);
}

// Round 2
// 652.034 us; speedup vs baseline: 1.0427x; 1.0427x over previous
//
#include <hip/hip_runtime.h>
#include <stdint.h>

// Magnitude pruning: mag = (t*magnitude + |x|)/(t+1); threshold = k-th smallest
// mag; out = x * (mag >= threshold). Exact selection via 2-level radix histogram
// (15 hi / 17 lo bits) on the monotonic unsigned key of mag.
// R1 fix: all streaming kernels issue 8 independent float4 loads per array per
// thread (MLP fix: 2 loads in flight -> 16); scans replaced by coalesced
// 64-segment reduce + tiny find kernel.

#define LO_BITS 17
#define NB_HI   (1 << (32 - LO_BITS))   // 32768 bins (top 15 bits)
#define NB_LO   (1 << LO_BITS)          // 131072 bins (low 17 bits)
#define NSEG    64

__device__ __forceinline__ uint32_t fkey(float f) {
    uint32_t u = __float_as_uint(f);
    return (u & 0x80000000u) ? ~u : (u | 0x80000000u);
}
__device__ __forceinline__ float magf(float x, float g, float tf, float den) {
    return (tf * g + fabsf(x)) / den;   // exact same arithmetic as reference
}

// ---------------- Pass 1: hi-15-bit histogram --------------------------------
// 1376 blocks x 1024 thr; each block owns 8192 contiguous float4 (32768 elems,
// so packed-u16 halves cannot overflow). 16 independent loads in flight/thread.
__global__ __launch_bounds__(1024) void hist_hi_kernel(
    const float* __restrict__ x, const float* __restrict__ g,
    const int* __restrict__ tptr, uint32_t* __restrict__ hist_hi, int n)
{
    __shared__ uint32_t lh[NB_HI / 2];
    for (int i = threadIdx.x; i < NB_HI / 2; i += 1024) lh[i] = 0;
    __syncthreads();
    const float tf  = (float)tptr[0];
    const float den = tf + 1.0f;
    const int n4 = n >> 2;
    const float4* x4 = (const float4*)x;
    const float4* g4 = (const float4*)g;
    const int base = blockIdx.x * 8192 + threadIdx.x;

    float4 xv[8], gv[8];
    #pragma unroll
    for (int u = 0; u < 8; ++u) {
        const int idx = base + u * 1024;
        if (idx < n4) { xv[u] = x4[idx]; gv[u] = g4[idx]; }
    }
    #pragma unroll
    for (int u = 0; u < 8; ++u) {
        const int idx = base + u * 1024;
        if (idx < n4) {
            uint32_t b0 = fkey(magf(xv[u].x, gv[u].x, tf, den)) >> LO_BITS;
            uint32_t b1 = fkey(magf(xv[u].y, gv[u].y, tf, den)) >> LO_BITS;
            uint32_t b2 = fkey(magf(xv[u].z, gv[u].z, tf, den)) >> LO_BITS;
            uint32_t b3 = fkey(magf(xv[u].w, gv[u].w, tf, den)) >> LO_BITS;
            atomicAdd(&lh[b0 >> 1], 1u << ((b0 & 1) * 16));
            atomicAdd(&lh[b1 >> 1], 1u << ((b1 & 1) * 16));
            atomicAdd(&lh[b2 >> 1], 1u << ((b2 & 1) * 16));
            atomicAdd(&lh[b3 >> 1], 1u << ((b3 & 1) * 16));
        }
    }
    // scalar tail (n % 4 elements), handled by block 0 only
    if (blockIdx.x == 0) {
        for (int i = (n4 << 2) + threadIdx.x; i < n; i += 1024) {
            uint32_t b = fkey(magf(x[i], g[i], tf, den)) >> LO_BITS;
            atomicAdd(&lh[b >> 1], 1u << ((b & 1) * 16));
        }
    }
    __syncthreads();
    for (int i = threadIdx.x; i < NB_HI / 2; i += 1024) {
        uint32_t v = lh[i];
        uint32_t lo = v & 0xffffu, hi = v >> 16;
        if (lo) atomicAdd(&hist_hi[2 * i],     lo);
        if (hi) atomicAdd(&hist_hi[2 * i + 1], hi);
    }
}

// ---------------- segment reduce (coalesced) ---------------------------------
__global__ __launch_bounds__(256) void seg_kernel(
    const uint32_t* __restrict__ hist, uint32_t* __restrict__ segsum, int bps)
{
    __shared__ uint32_t red[256];
    const int base = blockIdx.x * bps;
    uint32_t s = 0;
    for (int j = threadIdx.x; j < bps; j += 256) s += hist[base + j];
    red[threadIdx.x] = s;
    __syncthreads();
    for (int off = 128; off > 0; off >>= 1) {
        if (threadIdx.x < off) red[threadIdx.x] += red[threadIdx.x + off];
        __syncthreads();
    }
    if (threadIdx.x == 0) segsum[blockIdx.x] = red[0];
}

// ---------------- find crossing bin ------------------------------------------
// phase 0: kk from sparsity; writes ctl[0]=hi bin, ctl[1]=remaining rank.
// phase 1: kk = ctl[1];    writes ctl[2]=full 32-bit threshold key.
__global__ __launch_bounds__(1024) void find_kernel(
    const uint32_t* __restrict__ hist, const uint32_t* __restrict__ segsum,
    uint32_t* __restrict__ ctl, const float* __restrict__ sparsity,
    int nbins, int phase, int n)
{
    const int bps = nbins / NSEG;           // 512 (hi) or 2048 (lo)
    __shared__ uint32_t sseg[NSEG];
    __shared__ uint32_t bins[2048];
    __shared__ uint32_t scanbuf[1024];
    __shared__ uint32_t skk, sseg_id;
    const int tid = threadIdx.x;
    if (tid < NSEG) sseg[tid] = segsum[tid];
    __syncthreads();
    if (tid == 0) {
        uint32_t kk;
        if (phase == 0) {
            float s = sparsity[0];
            float v = floorf(s * (float)n - 1.0f);   // matches jnp f32 mul/sub/floor
            long long idx = (long long)v;
            if (idx < 0) idx = 0;
            if (idx > (long long)(n - 1)) idx = n - 1;
            kk = (uint32_t)(idx + 1);                // 1-based rank
        } else {
            kk = ctl[1];
        }
        uint32_t run = 0; uint32_t seg = NSEG - 1;
        for (int j = 0; j < NSEG; ++j) {
            if (run + sseg[j] >= kk) { seg = (uint32_t)j; break; }
            run += sseg[j];
        }
        skk = kk - run;                              // remaining rank in segment
        sseg_id = seg;
    }
    __syncthreads();
    const uint32_t kk = skk;
    const int seg = (int)sseg_id;
    for (int j = tid; j < bps; j += 1024) bins[j] = hist[seg * bps + j];
    __syncthreads();
    const int c = (bps + 1023) >> 10;                // 1 or 2 bins/thread
    uint32_t s = 0;
    for (int j = 0; j < c; ++j) {
        int b0 = tid * c + j;
        if (b0 < bps) s += bins[b0];
    }
    scanbuf[tid] = s;
    __syncthreads();
    for (int off = 1; off < 1024; off <<= 1) {       // Hillis-Steele inclusive
        uint32_t v = (tid >= off) ? scanbuf[tid - off] : 0u;
        __syncthreads();
        scanbuf[tid] += v;
        __syncthreads();
    }
    const uint32_t incl = scanbuf[tid];
    const uint32_t excl = incl - s;
    if (excl < kk && incl >= kk) {                   // exactly one thread
        uint32_t run = excl;
        for (int j = 0; j < c; ++j) {
            int b0 = tid * c + j;
            if (b0 < bps) {
                uint32_t cc = bins[b0];
                if (run + cc >= kk) {
                    uint32_t bin = (uint32_t)(seg * bps + b0);
                    if (phase == 0) { ctl[0] = bin; ctl[1] = kk - run; }
                    else            { ctl[2] = (ctl[0] << LO_BITS) | bin; }
                    break;
                }
                run += cc;
            }
        }
    }
}

// ---------------- Pass 2: lo-17-bit histogram of candidates ------------------
// 5504 blocks x 256 thr; block owns 2048 contiguous float4. Global atomics only
// for the (rare) elements whose hi bits match ctl[0].
__global__ __launch_bounds__(256) void hist_lo_kernel(
    const float* __restrict__ x, const float* __restrict__ g,
    const int* __restrict__ tptr, const uint32_t* __restrict__ ctl,
    uint32_t* __restrict__ hist_lo, int n)
{
    const uint32_t b   = ctl[0];
    const float tf  = (float)tptr[0];
    const float den = tf + 1.0f;
    const int n4 = n >> 2;
    const float4* x4 = (const float4*)x;
    const float4* g4 = (const float4*)g;
    const int base = blockIdx.x * 2048 + threadIdx.x;

    float4 xv[8], gv[8];
    #pragma unroll
    for (int u = 0; u < 8; ++u) {
        const int idx = base + u * 256;
        if (idx < n4) { xv[u] = x4[idx]; gv[u] = g4[idx]; }
    }
    #pragma unroll
    for (int u = 0; u < 8; ++u) {
        const int idx = base + u * 256;
        if (idx < n4) {
            uint32_t k0 = fkey(magf(xv[u].x, gv[u].x, tf, den));
            uint32_t k1 = fkey(magf(xv[u].y, gv[u].y, tf, den));
            uint32_t k2 = fkey(magf(xv[u].z, gv[u].z, tf, den));
            uint32_t k3 = fkey(magf(xv[u].w, gv[u].w, tf, den));
            if ((k0 >> LO_BITS) == b) atomicAdd(&hist_lo[k0 & (NB_LO - 1)], 1u);
            if ((k1 >> LO_BITS) == b) atomicAdd(&hist_lo[k1 & (NB_LO - 1)], 1u);
            if ((k2 >> LO_BITS) == b) atomicAdd(&hist_lo[k2 & (NB_LO - 1)], 1u);
            if ((k3 >> LO_BITS) == b) atomicAdd(&hist_lo[k3 & (NB_LO - 1)], 1u);
        }
    }
    if (blockIdx.x == 0) {
        for (int i = (n4 << 2) + threadIdx.x; i < n; i += 256) {
            uint32_t k = fkey(magf(x[i], g[i], tf, den));
            if ((k >> LO_BITS) == b) atomicAdd(&hist_lo[k & (NB_LO - 1)], 1u);
        }
    }
}

// ---------------- Pass 3: apply ----------------------------------------------
__global__ __launch_bounds__(256) void apply_kernel(
    const float* __restrict__ x, const float* __restrict__ g,
    const int* __restrict__ tptr, const uint32_t* __restrict__ ctl,
    float* __restrict__ out, int n)
{
    const uint32_t K = ctl[2];
    const float tf  = (float)tptr[0];
    const float den = tf + 1.0f;
    const int n4 = n >> 2;
    const float4* x4 = (const float4*)x;
    const float4* g4 = (const float4*)g;
    float4* o4 = (float4*)out;
    const int base = blockIdx.x * 2048 + threadIdx.x;

    float4 xv[8], gv[8];
    #pragma unroll
    for (int u = 0; u < 8; ++u) {
        const int idx = base + u * 256;
        if (idx < n4) { xv[u] = x4[idx]; gv[u] = g4[idx]; }
    }
    #pragma unroll
    for (int u = 0; u < 8; ++u) {
        const int idx = base + u * 256;
        if (idx < n4) {
            float4 o;
            o.x = xv[u].x * ((fkey(magf(xv[u].x, gv[u].x, tf, den)) >= K) ? 1.0f : 0.0f);
            o.y = xv[u].y * ((fkey(magf(xv[u].y, gv[u].y, tf, den)) >= K) ? 1.0f : 0.0f);
            o.z = xv[u].z * ((fkey(magf(xv[u].z, gv[u].z, tf, den)) >= K) ? 1.0f : 0.0f);
            o.w = xv[u].w * ((fkey(magf(xv[u].w, gv[u].w, tf, den)) >= K) ? 1.0f : 0.0f);
            o4[idx] = o;
        }
    }
    if (blockIdx.x == 0) {
        for (int i = (n4 << 2) + threadIdx.x; i < n; i += 256) {
            out[i] = x[i] * ((fkey(magf(x[i], g[i], tf, den)) >= K) ? 1.0f : 0.0f);
        }
    }
}

extern "C" void kernel_launch(void* const* d_in, const int* in_sizes, int n_in,
                              void* d_out, int out_size, void* d_ws, size_t ws_size,
                              hipStream_t stream)
{
    const float* x  = (const float*)d_in[0];
    const float* g  = (const float*)d_in[1];
    const float* sp = (const float*)d_in[2];
    // d_in[3] = mask input: unused by the reference computation.
    const int*   t  = (const int*)d_in[4];
    float* out = (float*)d_out;
    const int n  = in_sizes[0];
    const int n4 = n >> 2;

    uint32_t* hist_hi = (uint32_t*)d_ws;
    uint32_t* hist_lo = hist_hi + NB_HI;
    uint32_t* segsum  = hist_lo + NB_LO;
    uint32_t* ctl     = segsum + NSEG;   // ctl[0]=hi bin, ctl[1]=rem rank, ctl[2]=key

    hipMemsetAsync(d_ws, 0, (size_t)(NB_HI + NB_LO + NSEG + 3) * sizeof(uint32_t), stream);

    const int g_hi = (n4 + 8191) / 8192;     // 1376 for this shape
    const int g_lo = (n4 + 2047) / 2048;     // 5504 for this shape

    hist_hi_kernel<<<g_hi, 1024, 0, stream>>>(x, g, t, hist_hi, n);
    seg_kernel<<<NSEG, 256, 0, stream>>>(hist_hi, segsum, NB_HI / NSEG);
    find_kernel<<<1, 1024, 0, stream>>>(hist_hi, segsum, ctl, sp, NB_HI, 0, n);
    hist_lo_kernel<<<g_lo, 256, 0, stream>>>(x, g, t, ctl, hist_lo, n);
    seg_kernel<<<NSEG, 256, 0, stream>>>(hist_lo, segsum, NB_LO / NSEG);
    find_kernel<<<1, 1024, 0, stream>>>(hist_lo, segsum, ctl, sp, NB_LO, 1, n);
    apply_kernel<<<g_lo, 256, 0, stream>>>(x, g, t, ctl, out, n);
}